// Round 7
// baseline (1018.265 us; speedup 1.0000x reference)
//
#include <hip/hip_runtime.h>
#include <math.h>

// ============================================================================
// SimpleNTLBGModel: video frame top-6 selection + cross-attn + classifier
// Shapes: B=32 T=4096 D_IN=768 D=512 H=8 hd=64 K=6 L=512 V=1000
// R7 changes vs R6 (976 µs; 16-wave re-wave was neutral -> barrier domain,
// not intra-block TLP, is the limiter):
//   * score_gemm/logits_gemm: 64-row x 512-col blocks, 256 thr / 4 waves,
//     wave tile 64x128 (acc 4x8). LDS 74/72 KB, VGPR ~190 -> exactly
//     2 INDEPENDENT blocks/CU: one block computes while the other drains
//     at its barrier. Same k-order + epilogue summation order -> bit-identical.
//   * everything else verbatim R4/R6 (passed).
// ============================================================================

#define DEV __device__ __forceinline__

typedef _Float16 half8 __attribute__((ext_vector_type(8)));
typedef float f32x4v __attribute__((ext_vector_type(4)));

DEV unsigned short f2h_bits(float f) {
  union { _Float16 h; unsigned short u; } cv;
  cv.h = (_Float16)f;
  return cv.u;
}

// Direct global->LDS 16B async copy. lds base must be WAVE-UNIFORM; lane i
// deposits at lds + i*16. Global source is per-lane (pre-swizzled there).
DEV void gload16(const void* g, void* lds) {
  auto* gp = reinterpret_cast<const __attribute__((address_space(1))) unsigned int*>(
      reinterpret_cast<unsigned long long>(g));
  auto* lp = reinterpret_cast<__attribute__((address_space(3))) unsigned int*>(
      reinterpret_cast<unsigned long long>(lds));
  __builtin_amdgcn_global_load_lds(gp, lp, 16, 0, 0);
}

// ---------------------------------------------------------------------------
// 1. prep: fused independent preprocessing. (R2/R4, passed)
__global__ __launch_bounds__(256) void prep_k(
    const float* __restrict__ W_enc, unsigned short* __restrict__ WencT,
    const float* __restrict__ emb, const float* __restrict__ W_q,
    const float* __restrict__ b_q, float* __restrict__ Qe,
    const float* __restrict__ W_o, const float* __restrict__ W_cls,
    unsigned short* __restrict__ WocT, const float* __restrict__ b_o,
    const float* __restrict__ b_cls, float* __restrict__ boc) {
  __shared__ float plds[2080];              // 8320 B, shared by all phases
  const int blk = blockIdx.x, tid = threadIdx.x;
  if (blk < 96) {
    unsigned short* t = (unsigned short*)plds;    // [64][65]
    const int k0 = (blk % 12) * 64, n0 = (blk / 12) * 64;
    for (int e = tid; e < 4096; e += 256) {
      int kk = e >> 6, nn = e & 63;
      t[kk * 65 + nn] = f2h_bits(W_enc[(size_t)(k0 + kk) * 512 + n0 + nn]);
    }
    __syncthreads();
    for (int e = tid; e < 4096; e += 256) {
      int nn = e >> 6, kk = e & 63;
      WencT[(size_t)(n0 + nn) * 768 + k0 + kk] = t[kk * 65 + nn];
    }
  } else if (blk < 346) {
    float* er = plds;
    const int r0 = (blk - 96) * 4;
    for (int i = tid; i < 2048; i += 256) er[i] = emb[(size_t)r0 * 512 + i];
    __syncthreads();
    const int j0 = tid, j1 = tid + 256;
    float a0[4], a1[4];
#pragma unroll
    for (int r = 0; r < 4; ++r) { a0[r] = 0.f; a1[r] = 0.f; }
    for (int i = 0; i < 512; ++i) {
      float w0 = W_q[i * 512 + j0], w1 = W_q[i * 512 + j1];
#pragma unroll
      for (int r = 0; r < 4; ++r) {
        a0[r] += er[r * 512 + i] * w0;
        a1[r] += er[r * 512 + i] * w1;
      }
    }
    float bq0 = b_q[j0], bq1 = b_q[j1];
#pragma unroll
    for (int r = 0; r < 4; ++r) {
      Qe[(size_t)(r0 + r) * 512 + j0] = a0[r] + bq0;
      Qe[(size_t)(r0 + r) * 512 + j1] = a1[r] + bq1;
    }
  } else if (blk < 474) {
    float* wr = plds;
    const int i0 = (blk - 346) * 4;
    for (int i = tid; i < 2048; i += 256) wr[i] = W_o[(size_t)i0 * 512 + i];
    __syncthreads();
    float a[4][4];
#pragma unroll
    for (int r = 0; r < 4; ++r)
#pragma unroll
      for (int c = 0; c < 4; ++c) a[r][c] = 0.f;
    for (int m = 0; m < 512; ++m) {
      float wc[4];
#pragma unroll
      for (int c = 0; c < 4; ++c) {
        int j = tid + c * 256;
        wc[c] = (j < 1000) ? W_cls[(size_t)m * 1000 + j] : 0.f;
      }
#pragma unroll
      for (int r = 0; r < 4; ++r) {
        float x = wr[r * 512 + m];
#pragma unroll
        for (int c = 0; c < 4; ++c) a[r][c] += x * wc[c];
      }
    }
#pragma unroll
    for (int r = 0; r < 4; ++r)
#pragma unroll
      for (int c = 0; c < 4; ++c) {
        int j = tid + c * 256;
        if (j < 1000) WocT[(size_t)j * 512 + i0 + r] = f2h_bits(a[r][c]);
      }
    if (blk == 346) {  // zero pad rows 1000..1023
      for (int i = tid; i < 24 * 512; i += 256) WocT[512000 + i] = 0;
    }
  } else {
    int j = (blk - 474) * 256 + tid;        // 0..1023
    float s = 0.f;
    if (j < 1000) {
      for (int m = 0; m < 512; ++m) s += b_o[m] * W_cls[(size_t)m * 1000 + j];
      s += b_cls[j];
    }
    boc[j] = s;
  }
}

// ---------------------------------------------------------------------------
// 2. Fused score GEMM: 64-row tile, full N=512, BK=32, double-buffered.
//    256 thr / 4 waves; wave wv owns cols [wv*128, wv*128+128); acc 4x8.
//    2 independent blocks/CU (LDS 74 KB, VGPR<=256). Epilogue reproduces the
//    old 64-col-block summation order (part_lo/part_hi) -> bit-identical.
__global__ __launch_bounds__(256, 2) void score_gemm(
    const float* __restrict__ vf, const unsigned short* __restrict__ WencT,
    const float* __restrict__ b_enc, const float* __restrict__ W_sel,
    const float* __restrict__ b_sel, float* __restrict__ scores) {
  __shared__ unsigned short As[2][64 * 32];    // 2 x 4 KB, [row][k] swizzled
  __shared__ unsigned short Bs[2][512 * 32];   // 2 x 32 KB, [n][k] swizzled
  __shared__ float red[8 * 64];                // 2 KB

  const int tid = threadIdx.x;
  const int wv = tid >> 6, lane = tid & 63;
  const int quad = lane >> 4, l15 = lane & 15;
  const int rowBase = blockIdx.x * 64;
  const int rso = ((quad ^ (l15 & 3)) << 4);   // swizzled 16B read slot
  char* const AsB0 = (char*)As[0];
  char* const AsB1 = (char*)As[1];
  char* const BsB0 = (char*)Bs[0];
  char* const BsB1 = (char*)Bs[1];

  f32x4v acc[4][8];
#pragma unroll
  for (int i = 0; i < 4; ++i)
#pragma unroll
    for (int j = 0; j < 8; ++j) acc[i][j] = (f32x4v){0.f, 0.f, 0.f, 0.f};

  // A staging: thread owns row = tid>>2, 8-f32 segment aseg = tid&3.
  const int arow = tid >> 2, aseg = tid & 3;
  const float* aSrc = vf + (size_t)(rowBase + arow) * 768 + aseg * 8;
  const int adst = arow * 64 + ((aseg ^ (arow & 3)) << 4);

  auto packA = [&](float4 fa, float4 fb, char* An) {
    uint4 pk;
    pk.x = (unsigned int)f2h_bits(fa.x) | ((unsigned int)f2h_bits(fa.y) << 16);
    pk.y = (unsigned int)f2h_bits(fa.z) | ((unsigned int)f2h_bits(fa.w) << 16);
    pk.z = (unsigned int)f2h_bits(fb.x) | ((unsigned int)f2h_bits(fb.y) << 16);
    pk.w = (unsigned int)f2h_bits(fb.z) | ((unsigned int)f2h_bits(fb.w) << 16);
    *(uint4*)(An + adst) = pk;
  };
  auto stage_b = [&](int kk, char* dstB) {
#pragma unroll
    for (int it = 0; it < 8; ++it) {
      int q = tid + it * 256;
      int n = q >> 2, seg = q & 3;
      gload16(WencT + (size_t)n * 768 + kk * 32 + ((seg ^ (n & 3)) << 3),
              dstB + (it * 256 + wv * 64) * 16);
    }
  };
  auto consume = [&](const char* A, const char* B) {
    half8 af[4], bf[8];
#pragma unroll
    for (int i = 0; i < 4; ++i) {
      int row = 16 * i + l15;
      af[i] = *(const half8*)(A + row * 64 + rso);
    }
#pragma unroll
    for (int j = 0; j < 8; ++j) {
      int n = wv * 128 + 16 * j + l15;
      bf[j] = *(const half8*)(B + n * 64 + rso);
    }
#pragma unroll
    for (int i = 0; i < 4; ++i)
#pragma unroll
      for (int j = 0; j < 8; ++j)
        acc[i][j] = __builtin_amdgcn_mfma_f32_16x16x32_f16(af[i], bf[j], acc[i][j], 0, 0, 0);
  };

  // prologue: stage step 0 into buf0
  stage_b(0, BsB0);
  {
    float4 fa = *(const float4*)(aSrc);
    float4 fb = *(const float4*)(aSrc + 4);
    packA(fa, fb, AsB0);
  }
  __syncthreads();
  int cur = 0;
  for (int kk = 0; kk < 23; ++kk) {
    const float* s = aSrc + (kk + 1) * 32;
    float4 fa = *(const float4*)(s);         // issue vf loads early
    float4 fb = *(const float4*)(s + 4);
    char* An = cur ? AsB0 : AsB1;
    char* Bn = cur ? BsB0 : BsB1;
    stage_b(kk + 1, Bn);                     // async gloads into other buffer
    consume(cur ? AsB1 : AsB0, cur ? BsB1 : BsB0);
    packA(fa, fb, An);                       // pack+write after MFMAs
    __syncthreads();                         // drains vmem+lds for next step
    cur ^= 1;
  }
  consume(cur ? AsB1 : AsB0, cur ? BsB1 : BsB0);

  // epilogue: (x + b_enc) -> relu -> * W_sel -> reduce over cols.
  // part_lo == old col-block 2*wv (j=0..3), part_hi == old block 2*wv+1.
  float be[8], wsv[8];
#pragma unroll
  for (int j = 0; j < 8; ++j) {
    int col = wv * 128 + 16 * j + l15;
    be[j] = b_enc[col];
    wsv[j] = W_sel[col];
  }
  float plo[16], phi[16];
#pragma unroll
  for (int x = 0; x < 16; ++x) { plo[x] = 0.f; phi[x] = 0.f; }
#pragma unroll
  for (int i = 0; i < 4; ++i)
#pragma unroll
    for (int j = 0; j < 8; ++j)
#pragma unroll
      for (int r = 0; r < 4; ++r) {
        float v = acc[i][j][r] + be[j];   // row=16i+quad*4+r, col=wv*128+16j+l15
        v = fmaxf(v, 0.f);
        if (j < 4) plo[i * 4 + r] += v * wsv[j];
        else       phi[i * 4 + r] += v * wsv[j];
      }
#pragma unroll
  for (int m = 1; m < 16; m <<= 1)
#pragma unroll
    for (int x = 0; x < 16; ++x) {
      plo[x] += __shfl_xor(plo[x], m);
      phi[x] += __shfl_xor(phi[x], m);
    }
  if (l15 == 0) {
#pragma unroll
    for (int i = 0; i < 4; ++i)
#pragma unroll
      for (int r = 0; r < 4; ++r) {
        red[(2 * wv + 0) * 64 + 16 * i + quad * 4 + r] = plo[i * 4 + r];
        red[(2 * wv + 1) * 64 + 16 * i + quad * 4 + r] = phi[i * 4 + r];
      }
  }
  __syncthreads();
  if (tid < 64) {
    float s = 0.f;
#pragma unroll
    for (int ww = 0; ww < 8; ++ww) s += red[ww * 64 + tid];
    scores[rowBase + tid] = s + b_sel[0];
  }
}

// ---------------------------------------------------------------------------
// 3. per-batch top-16 candidates (R1 verbatim, passed). 256 threads.
__global__ __launch_bounds__(256) void topk16(const float* __restrict__ scores,
                                              int* __restrict__ cand) {
  __shared__ float swv[4];
  __shared__ int swi[4];
  __shared__ int winner;
  const int b = blockIdx.x, tid = threadIdx.x;
  const int lane = tid & 63, w = tid >> 6;
  float v[16];
#pragma unroll
  for (int p = 0; p < 16; ++p) v[p] = scores[b * 4096 + p * 256 + tid];
  for (int r = 0; r < 16; ++r) {
    // local argmax over 16 regs (ascending p => lowest index on ties)
    float bv = v[0];
    int bp = 0;
#pragma unroll
    for (int p = 1; p < 16; ++p)
      if (v[p] > bv) { bv = v[p]; bp = p; }
    int bi = bp * 256 + tid;
    // wave argmax (ties -> lower index)
#pragma unroll
    for (int m = 1; m < 64; m <<= 1) {
      float ov = __shfl_xor(bv, m);
      int oi = __shfl_xor(bi, m);
      if (ov > bv || (ov == bv && oi < bi)) { bv = ov; bi = oi; }
    }
    if (lane == 0) { swv[w] = bv; swi[w] = bi; }
    __syncthreads();
    if (tid == 0) {
      float fv = swv[0];
      int fi = swi[0];
#pragma unroll
      for (int x = 1; x < 4; ++x)
        if (swv[x] > fv || (swv[x] == fv && swi[x] < fi)) { fv = swv[x]; fi = swi[x]; }
      cand[b * 16 + r] = fi;
      winner = fi;
    }
    __syncthreads();
    const int wi = winner;
    const int wp = wi >> 8, wt = wi & 255;
#pragma unroll
    for (int p = 0; p < 16; ++p)
      if (p == wp && tid == wt) v[p] = -3.0e38f;
    __syncthreads();
  }
}

// ---------------------------------------------------------------------------
// 4. exact fp32 recompute for candidates (R1 verbatim, passed). grid (32,4).
__global__ __launch_bounds__(256) void rescore(
    const float* __restrict__ vf, const int* __restrict__ cand,
    const float* __restrict__ W_enc, const float* __restrict__ b_enc,
    const float* __restrict__ W_sel, const float* __restrict__ b_sel,
    float* __restrict__ veC, float* __restrict__ exsc) {
  __shared__ float vfs[4][768];             // 12 KB
  __shared__ float redl[16];
  const int b = blockIdx.x, cb = blockIdx.y * 4, tid = threadIdx.x;
  for (int c = 0; c < 4; ++c) {
    int t = cand[b * 16 + cb + c];
    const float* src = vf + ((size_t)b * 4096 + t) * 768;
    for (int i = tid; i < 768; i += 256) vfs[c][i] = src[i];
  }
  __syncthreads();
  const int j0 = tid, j1 = tid + 256;
  float a0[4] = {0.f, 0.f, 0.f, 0.f}, a1[4] = {0.f, 0.f, 0.f, 0.f};
  for (int i = 0; i < 768; ++i) {
    float w0 = W_enc[(size_t)i * 512 + j0], w1 = W_enc[(size_t)i * 512 + j1];
#pragma unroll
    for (int c = 0; c < 4; ++c) {
      float x = vfs[c][i];
      a0[c] += x * w0;
      a1[c] += x * w1;
    }
  }
  float ws0 = W_sel[j0], ws1 = W_sel[j1];
  float be0 = b_enc[j0], be1 = b_enc[j1];
  float s[4];
#pragma unroll
  for (int c = 0; c < 4; ++c) {
    float v0 = fmaxf(a0[c] + be0, 0.f);
    float v1 = fmaxf(a1[c] + be1, 0.f);
    veC[((size_t)b * 16 + cb + c) * 512 + j0] = v0;
    veC[((size_t)b * 16 + cb + c) * 512 + j1] = v1;
    s[c] = v0 * ws0 + v1 * ws1;
  }
#pragma unroll
  for (int m = 1; m < 64; m <<= 1)
#pragma unroll
    for (int c = 0; c < 4; ++c) s[c] += __shfl_xor(s[c], m);
  int w = tid >> 6;
  if ((tid & 63) == 0) {
#pragma unroll
    for (int c = 0; c < 4; ++c) redl[c * 4 + w] = s[c];
  }
  __syncthreads();
  if (tid < 4)
    exsc[b * 16 + cb + tid] = redl[tid * 4 + 0] + redl[tid * 4 + 1] +
                              redl[tid * 4 + 2] + redl[tid * 4 + 3] + b_sel[0];
}

// ---------------------------------------------------------------------------
// 5. stable top-6 by exact score + reps out (R1 verbatim, passed).
__global__ __launch_bounds__(256) void select6(
    const float* __restrict__ exsc, const int* __restrict__ cand,
    const float* __restrict__ veC, int* __restrict__ sel,
    float* __restrict__ repsOut) {
  __shared__ int selL[6];
  const int b = blockIdx.x, tid = threadIdx.x;
  if (tid == 0) {
    float v[16]; int idx[16]; bool used[16];
    for (int c = 0; c < 16; ++c) {
      v[c] = exsc[b * 16 + c];
      idx[c] = cand[b * 16 + c];
      used[c] = false;
    }
    for (int r = 0; r < 6; ++r) {
      int bi = -1;
      for (int c = 0; c < 16; ++c) {
        if (used[c]) continue;
        if (bi < 0 || v[c] > v[bi] || (v[c] == v[bi] && idx[c] < idx[bi])) bi = c;
      }
      used[bi] = true;
      selL[r] = bi;
      sel[b * 6 + r] = bi;
    }
  }
  __syncthreads();
  for (int r = 0; r < 6; ++r) {
    int c = selL[r];
    for (int i = tid; i < 512; i += 256)
      repsOut[((size_t)b * 6 + r) * 512 + i] = veC[((size_t)b * 16 + c) * 512 + i];
  }
}

// ---------------------------------------------------------------------------
// 6. k/v projections of reps (R1 verbatim, passed); 1/sqrt(64) folded into k.
__global__ __launch_bounds__(256) void kv_proj(
    const int* __restrict__ sel, const float* __restrict__ veC,
    const float* __restrict__ W_k, const float* __restrict__ W_v,
    const float* __restrict__ b_k, const float* __restrict__ b_v,
    float* __restrict__ Ks, float* __restrict__ Vs) {
  __shared__ float rep[512];
  const int br = blockIdx.x;                // b*6 + r
  const int b = br / 6;
  const int tid = threadIdx.x;
  const int c = sel[br];
  for (int i = tid; i < 512; i += 256) rep[i] = veC[((size_t)b * 16 + c) * 512 + i];
  __syncthreads();
  const int j0 = tid, j1 = tid + 256;
  float k0 = 0.f, k1 = 0.f, v0 = 0.f, v1 = 0.f;
  for (int m = 0; m < 512; ++m) {
    float x = rep[m];
    k0 += x * W_k[m * 512 + j0];
    k1 += x * W_k[m * 512 + j1];
    v0 += x * W_v[m * 512 + j0];
    v1 += x * W_v[m * 512 + j1];
  }
  Ks[(size_t)br * 512 + j0] = (k0 + b_k[j0]) * 0.125f;
  Ks[(size_t)br * 512 + j1] = (k1 + b_k[j1]) * 0.125f;
  Vs[(size_t)br * 512 + j0] = v0 + b_v[j0];
  Vs[(size_t)br * 512 + j1] = v1 + b_v[j1];
}

// ---------------------------------------------------------------------------
// 7. per-token attention over K=6 keys; one wave per token.
__global__ __launch_bounds__(256) void ctx_kernel(
    const int* __restrict__ ids, const float* __restrict__ Qe,
    const float* __restrict__ Ks, const float* __restrict__ Vs,
    unsigned short* __restrict__ CTX) {
  const int token = blockIdx.x * 4 + (threadIdx.x >> 6);
  const int lane = threadIdx.x & 63;
  const int b = token >> 9;                 // L = 512
  const int id = ids[token];
  float q[8];
#pragma unroll
  for (int h = 0; h < 8; ++h) q[h] = Qe[(size_t)id * 512 + h * 64 + lane];
  float s[8][6];
#pragma unroll
  for (int kk = 0; kk < 6; ++kk) {
    const float* kp = Ks + ((size_t)b * 6 + kk) * 512 + lane;
    float p[8];
#pragma unroll
    for (int h = 0; h < 8; ++h) p[h] = q[h] * kp[h * 64];
#pragma unroll
    for (int m = 1; m < 64; m <<= 1)
#pragma unroll
      for (int h = 0; h < 8; ++h) p[h] += __shfl_xor(p[h], m);
#pragma unroll
    for (int h = 0; h < 8; ++h) s[h][kk] = p[h];
  }
  const float* vbase = Vs + (size_t)b * 6 * 512 + lane;
#pragma unroll
  for (int h = 0; h < 8; ++h) {
    float mx = s[h][0];
#pragma unroll
    for (int kk = 1; kk < 6; ++kk) mx = fmaxf(mx, s[h][kk]);
    float e[6], sum = 0.f;
#pragma unroll
    for (int kk = 0; kk < 6; ++kk) { e[kk] = __expf(s[h][kk] - mx); sum += e[kk]; }
    float c = 0.f;
#pragma unroll
    for (int kk = 0; kk < 6; ++kk) c += e[kk] * vbase[(size_t)kk * 512 + h * 64];
    c *= (1.f / sum);
    CTX[(size_t)token * 512 + h * 64 + lane] = f2h_bits(c);
  }
}

// ---------------------------------------------------------------------------
// 8. logits = CTX @ W_oc + b_oc. 64-row tile, BK=32 dbuf, 256 thr / 4 waves,
//    wave tile 64x128 (acc 4x8), 2 independent blocks/CU. Bit-identical.
__global__ __launch_bounds__(256, 2) void logits_gemm(
    const unsigned short* __restrict__ CTX, const unsigned short* __restrict__ WocT,
    const float* __restrict__ boc, float* __restrict__ out) {
  __shared__ unsigned short As[2][64 * 32];    // 2 x 4 KB
  __shared__ unsigned short Bs[2][512 * 32];   // 2 x 32 KB
  const int tid = threadIdx.x;
  const int wv = tid >> 6, lane = tid & 63;
  const int quad = lane >> 4, l15 = lane & 15;
  const int rowBase = blockIdx.x * 64;
  const int n0 = blockIdx.y * 512;
  const int rso = ((quad ^ (l15 & 3)) << 4);
  char* const AsB0 = (char*)As[0];
  char* const AsB1 = (char*)As[1];
  char* const BsB0 = (char*)Bs[0];
  char* const BsB1 = (char*)Bs[1];

  f32x4v acc[4][8];
#pragma unroll
  for (int i = 0; i < 4; ++i)
#pragma unroll
    for (int j = 0; j < 8; ++j) acc[i][j] = (f32x4v){0.f, 0.f, 0.f, 0.f};

  const int arow = tid >> 2, aseg = tid & 3;

  auto stage = [&](int kk, char* An, char* Bn) {
    const int k0 = kk * 32;
    // A: 64x32 f16 = 256 chunks, 1 per thread
    gload16(CTX + (size_t)(rowBase + arow) * 512 + k0 + ((aseg ^ (arow & 3)) << 3),
            An + wv * 1024);
#pragma unroll
    for (int it = 0; it < 8; ++it) {             // B: 512x32 f16 = 2048 chunks
      int q = tid + it * 256;
      int n = q >> 2, seg = q & 3;
      gload16(WocT + (size_t)(n0 + n) * 512 + k0 + ((seg ^ (n & 3)) << 3),
              Bn + (it * 256 + wv * 64) * 16);
    }
  };
  auto consume = [&](const char* A, const char* B) {
    half8 af[4], bf[8];
#pragma unroll
    for (int i = 0; i < 4; ++i) {
      int row = 16 * i + l15;
      af[i] = *(const half8*)(A + row * 64 + rso);
    }
#pragma unroll
    for (int j = 0; j < 8; ++j) {
      int n = wv * 128 + 16 * j + l15;
      bf[j] = *(const half8*)(B + n * 64 + rso);
    }
#pragma unroll
    for (int i = 0; i < 4; ++i)
#pragma unroll
      for (int j = 0; j < 8; ++j)
        acc[i][j] = __builtin_amdgcn_mfma_f32_16x16x32_f16(af[i], bf[j], acc[i][j], 0, 0, 0);
  };

  stage(0, AsB0, BsB0);
  __syncthreads();
  int cur = 0;
  for (int kk = 0; kk < 15; ++kk) {
    stage(kk + 1, cur ? AsB0 : AsB1, cur ? BsB0 : BsB1);
    consume(cur ? AsB1 : AsB0, cur ? BsB1 : BsB0);
    __syncthreads();
    cur ^= 1;
  }
  consume(cur ? AsB1 : AsB0, cur ? BsB1 : BsB0);

  float bo[8];
#pragma unroll
  for (int j = 0; j < 8; ++j) bo[j] = boc[n0 + wv * 128 + 16 * j + l15];
#pragma unroll
  for (int i = 0; i < 4; ++i)
#pragma unroll
    for (int j = 0; j < 8; ++j)
#pragma unroll
      for (int r = 0; r < 4; ++r) {
        int token = rowBase + 16 * i + quad * 4 + r;
        int col = n0 + wv * 128 + 16 * j + l15;
        if (col < 1000) out[(size_t)token * 1000 + col] = acc[i][j][r] + bo[j];
      }
}

// ===========================================================================
extern "C" void kernel_launch(void* const* d_in, const int* in_sizes, int n_in,
                              void* d_out, int out_size, void* d_ws, size_t ws_size,
                              hipStream_t stream) {
  (void)in_sizes; (void)n_in; (void)out_size; (void)ws_size;
  const float* vf    = (const float*)d_in[0];
  const int*   ids   = (const int*)d_in[1];
  // d_in[2] attention_mask: unused by reference
  const float* W_enc = (const float*)d_in[3];
  const float* b_enc = (const float*)d_in[4];
  const float* W_sel = (const float*)d_in[5];
  const float* b_sel = (const float*)d_in[6];
  const float* emb   = (const float*)d_in[7];
  const float* W_q   = (const float*)d_in[8];
  const float* W_k   = (const float*)d_in[9];
  const float* W_v   = (const float*)d_in[10];
  const float* b_q   = (const float*)d_in[11];
  const float* b_k   = (const float*)d_in[12];
  const float* b_v   = (const float*)d_in[13];
  const float* W_o   = (const float*)d_in[14];
  const float* b_o   = (const float*)d_in[15];
  const float* W_cls = (const float*)d_in[16];
  const float* b_cls = (const float*)d_in[17];

  float* out = (float*)d_out;                  // logits [32*512*1000]
  float* reps_out = out + (size_t)16384000;    // reps   [32*6*512]

  // workspace carve-up (~24 MB)
  char* p = (char*)d_ws;
  auto nxt = [&](size_t bytes) -> char* {
    char* q = p;
    p += (bytes + 255) & ~(size_t)255;
    return q;
  };
  unsigned short* WencT = (unsigned short*)nxt((size_t)512 * 768 * 2);
  unsigned short* WocT  = (unsigned short*)nxt((size_t)1024 * 512 * 2);
  unsigned short* CTX   = (unsigned short*)nxt((size_t)16384 * 512 * 2);
  float* scores = (float*)nxt((size_t)131072 * 4);
  int*   cand   = (int*)nxt((size_t)512 * 4);
  float* exsc   = (float*)nxt((size_t)512 * 4);
  float* veC    = (float*)nxt((size_t)32 * 16 * 512 * 4);
  int*   sel    = (int*)nxt((size_t)192 * 4);
  float* Ks     = (float*)nxt((size_t)98304 * 4);
  float* Vs     = (float*)nxt((size_t)98304 * 4);
  float* Qe     = (float*)nxt((size_t)512000 * 4);
  float* boc    = (float*)nxt((size_t)1024 * 4);

  hipLaunchKernelGGL(prep_k,      dim3(478),    dim3(256), 0, stream,
                     W_enc, WencT, emb, W_q, b_q, Qe, W_o, W_cls, WocT, b_o, b_cls, boc);
  hipLaunchKernelGGL(score_gemm,  dim3(2048),   dim3(256), 0, stream,
                     vf, WencT, b_enc, W_sel, b_sel, scores);
  hipLaunchKernelGGL(topk16,      dim3(32),     dim3(256), 0, stream, scores, cand);
  hipLaunchKernelGGL(rescore,     dim3(32, 4),  dim3(256), 0, stream,
                     vf, cand, W_enc, b_enc, W_sel, b_sel, veC, exsc);
  hipLaunchKernelGGL(select6,     dim3(32),     dim3(256), 0, stream, exsc, cand, veC, sel, reps_out);
  hipLaunchKernelGGL(kv_proj,     dim3(192),    dim3(256), 0, stream, sel, veC, W_k, W_v, b_k, b_v, Ks, Vs);
  hipLaunchKernelGGL(ctx_kernel,  dim3(4096),   dim3(256), 0, stream, ids, Qe, Ks, Vs, CTX);
  hipLaunchKernelGGL(logits_gemm, dim3(256, 2), dim3(256), 0, stream, CTX, WocT, boc, out);
}

// Round 8
// 985.199 us; speedup vs baseline: 1.0336x; 1.0336x over previous
//
#include <hip/hip_runtime.h>
#include <math.h>

// ============================================================================
// SimpleNTLBGModel: video frame top-6 selection + cross-attn + classifier
// Shapes: B=32 T=4096 D_IN=768 D=512 H=8 hd=64 K=6 L=512 V=1000
// R8 changes vs R6 (976 µs best; R7's small-tile 2blk/CU regressed +42):
//   * B operands stored FRAGMENT-LINEAR ([n0g][kg][quad][l15][ki]) by prep_k;
//     score/logits read bf[j] as ONE coalesced 1KB wave-load from L2 --
//     no B LDS, no B staging (the cost common to R4-R7), no R5-style gather.
//     Same f16 values + k-order -> bit-identical outputs.
//   * GEMM skeleton = R6's 16-wave/128-row/BK=32/A-LDS-dbuf (best measured).
//   * select6+kv_proj merged into selkv_k (same sort/copy/chain order).
// ============================================================================

#define DEV __device__ __forceinline__

typedef _Float16 half8 __attribute__((ext_vector_type(8)));
typedef float f32x4v __attribute__((ext_vector_type(4)));

DEV unsigned short f2h_bits(float f) {
  union { _Float16 h; unsigned short u; } cv;
  cv.h = (_Float16)f;
  return cv.u;
}

// Direct global->LDS 16B async copy. lds base must be WAVE-UNIFORM; lane i
// deposits at lds + i*16. Global source is per-lane (pre-swizzled there).
DEV void gload16(const void* g, void* lds) {
  auto* gp = reinterpret_cast<const __attribute__((address_space(1))) unsigned int*>(
      reinterpret_cast<unsigned long long>(g));
  auto* lp = reinterpret_cast<__attribute__((address_space(3))) unsigned int*>(
      reinterpret_cast<unsigned long long>(lds));
  __builtin_amdgcn_global_load_lds(gp, lp, 16, 0, 0);
}

// ---------------------------------------------------------------------------
// 1. prep: fused independent preprocessing.
//    blocks [0,96):   W_enc f32 -> WencF fragment-linear f16
//                     WencF[((n/16)*24 + k/32)*512 + (k%32/8)*128 + (n%16)*8 + k%8]
//    blocks [96,346): Qe = emb@W_q + b_q   (4 rows/block)
//    blocks [346,474): WocF = (W_o@W_cls)^T fragment-linear f16 (n pad 1024)
//                     WocF[((n/16)*16 + k/32)*512 + (k%32/8)*128 + (n%16)*8 + k%8]
//    blocks [474,478): b_oc = b_o@W_cls + b_cls (1024 padded)
__global__ __launch_bounds__(256) void prep_k(
    const float* __restrict__ W_enc, unsigned short* __restrict__ WencF,
    const float* __restrict__ emb, const float* __restrict__ W_q,
    const float* __restrict__ b_q, float* __restrict__ Qe,
    const float* __restrict__ W_o, const float* __restrict__ W_cls,
    unsigned short* __restrict__ WocF, const float* __restrict__ b_o,
    const float* __restrict__ b_cls, float* __restrict__ boc) {
  __shared__ float plds[2080];              // 8320 B, shared by all phases
  const int blk = blockIdx.x, tid = threadIdx.x;
  if (blk < 96) {
    unsigned short* t = (unsigned short*)plds;    // [64][65]
    const int k0 = (blk % 12) * 64, n0 = (blk / 12) * 64;
    for (int e = tid; e < 4096; e += 256) {
      int kk = e >> 6, nn = e & 63;
      t[kk * 65 + nn] = f2h_bits(W_enc[(size_t)(k0 + kk) * 512 + n0 + nn]);
    }
    __syncthreads();
    // write 8 fragments (4 n-groups x 2 k-groups), coalesced out
    for (int e = tid; e < 4096; e += 256) {
      int frag = e >> 9, within = e & 511;
      int n0g = frag >> 1, kg = frag & 1;
      int quad = within >> 7, l15 = (within >> 3) & 15, ki = within & 7;
      WencF[(size_t)(((n0 >> 4) + n0g) * 24 + (k0 >> 5) + kg) * 512 + within] =
          t[(kg * 32 + quad * 8 + ki) * 65 + n0g * 16 + l15];
    }
  } else if (blk < 346) {
    float* er = plds;
    const int r0 = (blk - 96) * 4;
    for (int i = tid; i < 2048; i += 256) er[i] = emb[(size_t)r0 * 512 + i];
    __syncthreads();
    const int j0 = tid, j1 = tid + 256;
    float a0[4], a1[4];
#pragma unroll
    for (int r = 0; r < 4; ++r) { a0[r] = 0.f; a1[r] = 0.f; }
    for (int i = 0; i < 512; ++i) {
      float w0 = W_q[i * 512 + j0], w1 = W_q[i * 512 + j1];
#pragma unroll
      for (int r = 0; r < 4; ++r) {
        a0[r] += er[r * 512 + i] * w0;
        a1[r] += er[r * 512 + i] * w1;
      }
    }
    float bq0 = b_q[j0], bq1 = b_q[j1];
#pragma unroll
    for (int r = 0; r < 4; ++r) {
      Qe[(size_t)(r0 + r) * 512 + j0] = a0[r] + bq0;
      Qe[(size_t)(r0 + r) * 512 + j1] = a1[r] + bq1;
    }
  } else if (blk < 474) {
    float* wr = plds;
    const int i0 = (blk - 346) * 4;       // k rows
    for (int i = tid; i < 2048; i += 256) wr[i] = W_o[(size_t)i0 * 512 + i];
    __syncthreads();
    float a[4][4];
#pragma unroll
    for (int r = 0; r < 4; ++r)
#pragma unroll
      for (int c = 0; c < 4; ++c) a[r][c] = 0.f;
    for (int m = 0; m < 512; ++m) {
      float wc[4];
#pragma unroll
      for (int c = 0; c < 4; ++c) {
        int j = tid + c * 256;
        wc[c] = (j < 1000) ? W_cls[(size_t)m * 1000 + j] : 0.f;
      }
#pragma unroll
      for (int r = 0; r < 4; ++r) {
        float x = wr[r * 512 + m];
#pragma unroll
        for (int c = 0; c < 4; ++c) a[r][c] += x * wc[c];
      }
    }
#pragma unroll
    for (int r = 0; r < 4; ++r)
#pragma unroll
      for (int c = 0; c < 4; ++c) {
        int j = tid + c * 256;             // n
        int k = i0 + r;
        if (j < 1000)
          WocF[(size_t)((j >> 4) * 16 + (k >> 5)) * 512 +
               (((k >> 3) & 3) << 7) + ((j & 15) << 3) + (k & 7)] = f2h_bits(a[r][c]);
      }
    if (blk == 346) {  // zero pad n = 1000..1023, all k
      for (int e = tid; e < 24 * 512; e += 256) {
        int n = 1000 + (e >> 9), k = e & 511;
        WocF[(size_t)((n >> 4) * 16 + (k >> 5)) * 512 +
             (((k >> 3) & 3) << 7) + ((n & 15) << 3) + (k & 7)] = 0;
      }
    }
  } else {
    int j = (blk - 474) * 256 + tid;        // 0..1023
    float s = 0.f;
    if (j < 1000) {
      for (int m = 0; m < 512; ++m) s += b_o[m] * W_cls[(size_t)m * 1000 + j];
      s += b_cls[j];
    }
    boc[j] = s;
  }
}

// ---------------------------------------------------------------------------
// 2. Fused score GEMM: 128-row tile, full N=512, BK=32, A-LDS dbuf (R6
//    skeleton). B read directly from fragment-linear WencF: one coalesced
//    1KB wave-load per bf[j]. 16 waves; wave (wr,wc); acc 4x4.
__global__ __launch_bounds__(1024, 4) void score_gemm(
    const float* __restrict__ vf, const unsigned short* __restrict__ WencF,
    const float* __restrict__ b_enc, const float* __restrict__ W_sel,
    const float* __restrict__ b_sel, float* __restrict__ scores) {
  __shared__ unsigned short As[2][128 * 32];   // 2 x 8 KB, [row][k] swizzled
  __shared__ float red[16 * 64];               // 4 KB

  const int tid = threadIdx.x;
  const int wv = tid >> 6, lane = tid & 63;
  const int quad = lane >> 4, l15 = lane & 15;
  const int wr = wv >> 3, wc = wv & 7;         // wave row-half / col-block
  const int rowBase = blockIdx.x * 128;
  const int rso = ((quad ^ (l15 & 3)) << 4);   // swizzled 16B read slot
  char* const AsB0 = (char*)As[0];
  char* const AsB1 = (char*)As[1];

  f32x4v acc[4][4];
#pragma unroll
  for (int i = 0; i < 4; ++i)
#pragma unroll
    for (int j = 0; j < 4; ++j) acc[i][j] = (f32x4v){0.f, 0.f, 0.f, 0.f};

  // A staging: thread owns row = tid>>3, 4-f32 segment aseg = tid&7.
  const int arow = tid >> 3, aseg = tid & 7;
  const float* aSrc = vf + (size_t)(rowBase + arow) * 768 + aseg * 4;
  const int aslot = aseg >> 1, ahalf = aseg & 1;
  const int adst = arow * 64 + ((aslot ^ (arow & 3)) << 4) + ahalf * 8;

  auto packA = [&](float4 f, char* An) {
    uint2 pk;
    pk.x = (unsigned int)f2h_bits(f.x) | ((unsigned int)f2h_bits(f.y) << 16);
    pk.y = (unsigned int)f2h_bits(f.z) | ((unsigned int)f2h_bits(f.w) << 16);
    *(uint2*)(An + adst) = pk;
  };
  // B fragment bases: wave-uniform, lane*16B within
  const unsigned short* const bBase = WencF + (size_t)lane * 8;
  auto consume = [&](const char* A, int kk) {
    half8 af[4], bf[4];
#pragma unroll
    for (int j = 0; j < 4; ++j)
      bf[j] = *(const half8*)(bBase + (size_t)((wc * 4 + j) * 24 + kk) * 512);
#pragma unroll
    for (int i = 0; i < 4; ++i) {
      int row = wr * 64 + 16 * i + l15;
      af[i] = *(const half8*)(A + row * 64 + rso);
    }
#pragma unroll
    for (int i = 0; i < 4; ++i)
#pragma unroll
      for (int j = 0; j < 4; ++j)
        acc[i][j] = __builtin_amdgcn_mfma_f32_16x16x32_f16(af[i], bf[j], acc[i][j], 0, 0, 0);
  };

  // prologue: stage A step 0 into buf0
  packA(*(const float4*)(aSrc), AsB0);
  __syncthreads();
  int cur = 0;
  for (int kk = 0; kk < 23; ++kk) {
    float4 fa = *(const float4*)(aSrc + (kk + 1) * 32);   // issue vf load early
    char* An = cur ? AsB0 : AsB1;
    consume(cur ? AsB1 : AsB0, kk);
    packA(fa, An);                           // pack+write after MFMAs
    __syncthreads();
    cur ^= 1;
  }
  consume(cur ? AsB1 : AsB0, 23);

  // epilogue: (x + b_enc) -> relu -> * W_sel -> reduce over cols (== R6 order)
  float be[4], wsv[4];
#pragma unroll
  for (int j = 0; j < 4; ++j) {
    int col = wc * 64 + 16 * j + l15;
    be[j] = b_enc[col];
    wsv[j] = W_sel[col];
  }
  float part[16];
#pragma unroll
  for (int x = 0; x < 16; ++x) part[x] = 0.f;
#pragma unroll
  for (int i = 0; i < 4; ++i)
#pragma unroll
    for (int j = 0; j < 4; ++j)
#pragma unroll
      for (int r = 0; r < 4; ++r) {
        float v = acc[i][j][r] + be[j];   // row=wr*64+16i+quad*4+r, col=wc*64+16j+l15
        v = fmaxf(v, 0.f);
        part[i * 4 + r] += v * wsv[j];
      }
#pragma unroll
  for (int m = 1; m < 16; m <<= 1)
#pragma unroll
    for (int x = 0; x < 16; ++x) part[x] += __shfl_xor(part[x], m);
  if (l15 == 0) {
#pragma unroll
    for (int i = 0; i < 4; ++i)
#pragma unroll
      for (int r = 0; r < 4; ++r)
        red[wv * 64 + 16 * i + quad * 4 + r] = part[i * 4 + r];
  }
  __syncthreads();
  if (tid < 128) {
    const int rh = tid >> 6, rl = tid & 63;
    float s = 0.f;
#pragma unroll
    for (int ww = 0; ww < 8; ++ww) s += red[(rh * 8 + ww) * 64 + rl];
    scores[rowBase + tid] = s + b_sel[0];
  }
}

// ---------------------------------------------------------------------------
// 3. per-batch top-16 candidates (R1 verbatim, passed). 256 threads.
__global__ __launch_bounds__(256) void topk16(const float* __restrict__ scores,
                                              int* __restrict__ cand) {
  __shared__ float swv[4];
  __shared__ int swi[4];
  __shared__ int winner;
  const int b = blockIdx.x, tid = threadIdx.x;
  const int lane = tid & 63, w = tid >> 6;
  float v[16];
#pragma unroll
  for (int p = 0; p < 16; ++p) v[p] = scores[b * 4096 + p * 256 + tid];
  for (int r = 0; r < 16; ++r) {
    float bv = v[0];
    int bp = 0;
#pragma unroll
    for (int p = 1; p < 16; ++p)
      if (v[p] > bv) { bv = v[p]; bp = p; }
    int bi = bp * 256 + tid;
#pragma unroll
    for (int m = 1; m < 64; m <<= 1) {
      float ov = __shfl_xor(bv, m);
      int oi = __shfl_xor(bi, m);
      if (ov > bv || (ov == bv && oi < bi)) { bv = ov; bi = oi; }
    }
    if (lane == 0) { swv[w] = bv; swi[w] = bi; }
    __syncthreads();
    if (tid == 0) {
      float fv = swv[0];
      int fi = swi[0];
#pragma unroll
      for (int x = 1; x < 4; ++x)
        if (swv[x] > fv || (swv[x] == fv && swi[x] < fi)) { fv = swv[x]; fi = swi[x]; }
      cand[b * 16 + r] = fi;
      winner = fi;
    }
    __syncthreads();
    const int wi = winner;
    const int wp = wi >> 8, wt = wi & 255;
#pragma unroll
    for (int p = 0; p < 16; ++p)
      if (p == wp && tid == wt) v[p] = -3.0e38f;
    __syncthreads();
  }
}

// ---------------------------------------------------------------------------
// 4. exact fp32 recompute for candidates (R1 verbatim, passed). grid (32,4).
__global__ __launch_bounds__(256) void rescore(
    const float* __restrict__ vf, const int* __restrict__ cand,
    const float* __restrict__ W_enc, const float* __restrict__ b_enc,
    const float* __restrict__ W_sel, const float* __restrict__ b_sel,
    float* __restrict__ veC, float* __restrict__ exsc) {
  __shared__ float vfs[4][768];             // 12 KB
  __shared__ float redl[16];
  const int b = blockIdx.x, cb = blockIdx.y * 4, tid = threadIdx.x;
  for (int c = 0; c < 4; ++c) {
    int t = cand[b * 16 + cb + c];
    const float* src = vf + ((size_t)b * 4096 + t) * 768;
    for (int i = tid; i < 768; i += 256) vfs[c][i] = src[i];
  }
  __syncthreads();
  const int j0 = tid, j1 = tid + 256;
  float a0[4] = {0.f, 0.f, 0.f, 0.f}, a1[4] = {0.f, 0.f, 0.f, 0.f};
  for (int i = 0; i < 768; ++i) {
    float w0 = W_enc[(size_t)i * 512 + j0], w1 = W_enc[(size_t)i * 512 + j1];
#pragma unroll
    for (int c = 0; c < 4; ++c) {
      float x = vfs[c][i];
      a0[c] += x * w0;
      a1[c] += x * w1;
    }
  }
  float ws0 = W_sel[j0], ws1 = W_sel[j1];
  float be0 = b_enc[j0], be1 = b_enc[j1];
  float s[4];
#pragma unroll
  for (int c = 0; c < 4; ++c) {
    float v0 = fmaxf(a0[c] + be0, 0.f);
    float v1 = fmaxf(a1[c] + be1, 0.f);
    veC[((size_t)b * 16 + cb + c) * 512 + j0] = v0;
    veC[((size_t)b * 16 + cb + c) * 512 + j1] = v1;
    s[c] = v0 * ws0 + v1 * ws1;
  }
#pragma unroll
  for (int m = 1; m < 64; m <<= 1)
#pragma unroll
    for (int c = 0; c < 4; ++c) s[c] += __shfl_xor(s[c], m);
  int w = tid >> 6;
  if ((tid & 63) == 0) {
#pragma unroll
    for (int c = 0; c < 4; ++c) redl[c * 4 + w] = s[c];
  }
  __syncthreads();
  if (tid < 4)
    exsc[b * 16 + cb + tid] = redl[tid * 4 + 0] + redl[tid * 4 + 1] +
                              redl[tid * 4 + 2] + redl[tid * 4 + 3] + b_sel[0];
}

// ---------------------------------------------------------------------------
// 5. merged select6 + kv_proj: one block per (b, rank). tid==0 redoes the
//    stable top-6 scan to rank rk (same compare order as select6 -> same
//    result); block copies reps row + computes k/v row (same chains as
//    kv_proj, 1/sqrt(64) folded into k).
__global__ __launch_bounds__(256) void selkv_k(
    const float* __restrict__ exsc, const int* __restrict__ cand,
    const float* __restrict__ veC, const float* __restrict__ W_k,
    const float* __restrict__ W_v, const float* __restrict__ b_k,
    const float* __restrict__ b_v, float* __restrict__ repsOut,
    float* __restrict__ Ks, float* __restrict__ Vs) {
  __shared__ float rep[512];
  __shared__ int selc;
  const int br = blockIdx.x;                // b*6 + rk
  const int b = br / 6, rk = br - b * 6;
  const int tid = threadIdx.x;
  if (tid == 0) {
    float v[16]; int idx[16]; bool used[16];
    for (int c = 0; c < 16; ++c) {
      v[c] = exsc[b * 16 + c];
      idx[c] = cand[b * 16 + c];
      used[c] = false;
    }
    int bi = -1;
    for (int r = 0; r <= rk; ++r) {
      bi = -1;
      for (int c = 0; c < 16; ++c) {
        if (used[c]) continue;
        if (bi < 0 || v[c] > v[bi] || (v[c] == v[bi] && idx[c] < idx[bi])) bi = c;
      }
      used[bi] = true;
    }
    selc = bi;
  }
  __syncthreads();
  const int c = selc;
  for (int i = tid; i < 512; i += 256) {
    float x = veC[((size_t)b * 16 + c) * 512 + i];
    repsOut[((size_t)b * 6 + rk) * 512 + i] = x;
    rep[i] = x;
  }
  __syncthreads();
  const int j0 = tid, j1 = tid + 256;
  float k0 = 0.f, k1 = 0.f, v0 = 0.f, v1 = 0.f;
  for (int m = 0; m < 512; ++m) {
    float x = rep[m];
    k0 += x * W_k[m * 512 + j0];
    k1 += x * W_k[m * 512 + j1];
    v0 += x * W_v[m * 512 + j0];
    v1 += x * W_v[m * 512 + j1];
  }
  Ks[(size_t)br * 512 + j0] = (k0 + b_k[j0]) * 0.125f;
  Ks[(size_t)br * 512 + j1] = (k1 + b_k[j1]) * 0.125f;
  Vs[(size_t)br * 512 + j0] = v0 + b_v[j0];
  Vs[(size_t)br * 512 + j1] = v1 + b_v[j1];
}

// ---------------------------------------------------------------------------
// 6. per-token attention over K=6 keys; one wave per token.
__global__ __launch_bounds__(256) void ctx_kernel(
    const int* __restrict__ ids, const float* __restrict__ Qe,
    const float* __restrict__ Ks, const float* __restrict__ Vs,
    unsigned short* __restrict__ CTX) {
  const int token = blockIdx.x * 4 + (threadIdx.x >> 6);
  const int lane = threadIdx.x & 63;
  const int b = token >> 9;                 // L = 512
  const int id = ids[token];
  float q[8];
#pragma unroll
  for (int h = 0; h < 8; ++h) q[h] = Qe[(size_t)id * 512 + h * 64 + lane];
  float s[8][6];
#pragma unroll
  for (int kk = 0; kk < 6; ++kk) {
    const float* kp = Ks + ((size_t)b * 6 + kk) * 512 + lane;
    float p[8];
#pragma unroll
    for (int h = 0; h < 8; ++h) p[h] = q[h] * kp[h * 64];
#pragma unroll
    for (int m = 1; m < 64; m <<= 1)
#pragma unroll
      for (int h = 0; h < 8; ++h) p[h] += __shfl_xor(p[h], m);
#pragma unroll
    for (int h = 0; h < 8; ++h) s[h][kk] = p[h];
  }
  const float* vbase = Vs + (size_t)b * 6 * 512 + lane;
#pragma unroll
  for (int h = 0; h < 8; ++h) {
    float mx = s[h][0];
#pragma unroll
    for (int kk = 1; kk < 6; ++kk) mx = fmaxf(mx, s[h][kk]);
    float e[6], sum = 0.f;
#pragma unroll
    for (int kk = 0; kk < 6; ++kk) { e[kk] = __expf(s[h][kk] - mx); sum += e[kk]; }
    float c = 0.f;
#pragma unroll
    for (int kk = 0; kk < 6; ++kk) c += e[kk] * vbase[(size_t)kk * 512 + h * 64];
    c *= (1.f / sum);
    CTX[(size_t)token * 512 + h * 64 + lane] = f2h_bits(c);
  }
}

// ---------------------------------------------------------------------------
// 7. logits = CTX @ W_oc + b_oc. R6 skeleton (16 waves, 128-row, BK=32,
//    A gload_lds dbuf); B direct from fragment-linear WocF (coalesced).
__global__ __launch_bounds__(1024, 4) void logits_gemm(
    const unsigned short* __restrict__ CTX, const unsigned short* __restrict__ WocF,
    const float* __restrict__ boc, float* __restrict__ out) {
  __shared__ unsigned short As[2][128 * 32];   // 2 x 8 KB
  const int tid = threadIdx.x;
  const int wv = tid >> 6, lane = tid & 63;
  const int quad = lane >> 4, l15 = lane & 15;
  const int wr = wv >> 3, wc = wv & 7;
  const int rowBase = blockIdx.x * 128;
  const int n0 = blockIdx.y * 512;
  const int rso = ((quad ^ (l15 & 3)) << 4);
  char* const AsB0 = (char*)As[0];
  char* const AsB1 = (char*)As[1];

  f32x4v acc[4][4];
#pragma unroll
  for (int i = 0; i < 4; ++i)
#pragma unroll
    for (int j = 0; j < 4; ++j) acc[i][j] = (f32x4v){0.f, 0.f, 0.f, 0.f};

  const int arow = tid >> 2, aseg = tid & 3;   // valid for tid<512

  auto stageA = [&](int kk, char* An) {
    const int k0 = kk * 32;
    if (wv < 8) {                              // A: 128x32 f16 = 512 chunks
      gload16(CTX + (size_t)(rowBase + arow) * 512 + k0 + ((aseg ^ (arow & 3)) << 3),
              An + wv * 1024);
    }
  };
  const unsigned short* const bBase = WocF + (size_t)lane * 8;
  const int nG = (n0 >> 4) + wc * 4;           // n-group base for this wave
  auto consume = [&](const char* A, int kk) {
    half8 af[4], bf[4];
#pragma unroll
    for (int j = 0; j < 4; ++j)
      bf[j] = *(const half8*)(bBase + (size_t)((nG + j) * 16 + kk) * 512);
#pragma unroll
    for (int i = 0; i < 4; ++i) {
      int row = wr * 64 + 16 * i + l15;
      af[i] = *(const half8*)(A + row * 64 + rso);
    }
#pragma unroll
    for (int i = 0; i < 4; ++i)
#pragma unroll
      for (int j = 0; j < 4; ++j)
        acc[i][j] = __builtin_amdgcn_mfma_f32_16x16x32_f16(af[i], bf[j], acc[i][j], 0, 0, 0);
  };

  stageA(0, AsB0);
  __syncthreads();
  int cur = 0;
  for (int kk = 0; kk < 15; ++kk) {
    stageA(kk + 1, cur ? AsB0 : AsB1);
    consume(cur ? AsB1 : AsB0, kk);
    __syncthreads();
    cur ^= 1;
  }
  consume(cur ? AsB1 : AsB0, 15);

  float bo[4];
#pragma unroll
  for (int j = 0; j < 4; ++j) bo[j] = boc[n0 + wc * 64 + 16 * j + l15];
#pragma unroll
  for (int i = 0; i < 4; ++i)
#pragma unroll
    for (int j = 0; j < 4; ++j)
#pragma unroll
      for (int r = 0; r < 4; ++r) {
        int token = rowBase + wr * 64 + 16 * i + quad * 4 + r;
        int col = n0 + wc * 64 + 16 * j + l15;
        if (col < 1000) out[(size_t)token * 1000 + col] = acc[i][j][r] + bo[j];
      }
}

// ===========================================================================
extern "C" void kernel_launch(void* const* d_in, const int* in_sizes, int n_in,
                              void* d_out, int out_size, void* d_ws, size_t ws_size,
                              hipStream_t stream) {
  (void)in_sizes; (void)n_in; (void)out_size; (void)ws_size;
  const float* vf    = (const float*)d_in[0];
  const int*   ids   = (const int*)d_in[1];
  // d_in[2] attention_mask: unused by reference
  const float* W_enc = (const float*)d_in[3];
  const float* b_enc = (const float*)d_in[4];
  const float* W_sel = (const float*)d_in[5];
  const float* b_sel = (const float*)d_in[6];
  const float* emb   = (const float*)d_in[7];
  const float* W_q   = (const float*)d_in[8];
  const float* W_k   = (const float*)d_in[9];
  const float* W_v   = (const float*)d_in[10];
  const float* b_q   = (const float*)d_in[11];
  const float* b_k   = (const float*)d_in[12];
  const float* b_v   = (const float*)d_in[13];
  const float* W_o   = (const float*)d_in[14];
  const float* b_o   = (const float*)d_in[15];
  const float* W_cls = (const float*)d_in[16];
  const float* b_cls = (const float*)d_in[17];

  float* out = (float*)d_out;                  // logits [32*512*1000]
  float* reps_out = out + (size_t)16384000;    // reps   [32*6*512]

  // workspace carve-up (~24 MB)
  char* p = (char*)d_ws;
  auto nxt = [&](size_t bytes) -> char* {
    char* q = p;
    p += (bytes + 255) & ~(size_t)255;
    return q;
  };
  unsigned short* WencF = (unsigned short*)nxt((size_t)512 * 768 * 2);
  unsigned short* WocF  = (unsigned short*)nxt((size_t)1024 * 512 * 2);
  unsigned short* CTX   = (unsigned short*)nxt((size_t)16384 * 512 * 2);
  float* scores = (float*)nxt((size_t)131072 * 4);
  int*   cand   = (int*)nxt((size_t)512 * 4);
  float* exsc   = (float*)nxt((size_t)512 * 4);
  float* veC    = (float*)nxt((size_t)32 * 16 * 512 * 4);
  float* Ks     = (float*)nxt((size_t)98304 * 4);
  float* Vs     = (float*)nxt((size_t)98304 * 4);
  float* Qe     = (float*)nxt((size_t)512000 * 4);
  float* boc    = (float*)nxt((size_t)1024 * 4);

  hipLaunchKernelGGL(prep_k,      dim3(478),    dim3(256), 0, stream,
                     W_enc, WencF, emb, W_q, b_q, Qe, W_o, W_cls, WocF, b_o, b_cls, boc);
  hipLaunchKernelGGL(score_gemm,  dim3(1024),   dim3(1024), 0, stream,
                     vf, WencF, b_enc, W_sel, b_sel, scores);
  hipLaunchKernelGGL(topk16,      dim3(32),     dim3(256), 0, stream, scores, cand);
  hipLaunchKernelGGL(rescore,     dim3(32, 4),  dim3(256), 0, stream,
                     vf, cand, W_enc, b_enc, W_sel, b_sel, veC, exsc);
  hipLaunchKernelGGL(selkv_k,     dim3(192),    dim3(256), 0, stream,
                     exsc, cand, veC, W_k, W_v, b_k, b_v, reps_out, Ks, Vs);
  hipLaunchKernelGGL(ctx_kernel,  dim3(4096),   dim3(256), 0, stream, ids, Qe, Ks, Vs, CTX);
  hipLaunchKernelGGL(logits_gemm, dim3(128, 2), dim3(1024), 0, stream, CTX, WocF, boc, out);
}

// Round 9
// 946.044 us; speedup vs baseline: 1.0763x; 1.0414x over previous
//
#include <hip/hip_runtime.h>
#include <math.h>

// ============================================================================
// SimpleNTLBGModel: video frame top-6 selection + cross-attn + classifier
// Shapes: B=32 T=4096 D_IN=768 D=512 H=8 hd=64 K=6 L=512 V=1000
// R9 = best-of-measured assembly:
//   * prep_k / score_gemm / logits_gemm: R6 verbatim (best GEMM variant, 976.6;
//     R5/R7/R8 restructures were all neutral-to-negative -> structure plateau).
//   * rescore: widened (32,4)->(32,16), 1 candidate/block (512 blocks = 2/CU,
//     was 128 blocks = half GPU idle). Built from R1's proven kernel by
//     removing the c-loop; per-candidate chains unchanged -> bit-identical.
//   * selkv_k: R8's merged select6+kv_proj (passed).
//   * topk16 / ctx_kernel: R1/R4 verbatim.
// ============================================================================

#define DEV __device__ __forceinline__

typedef _Float16 half8 __attribute__((ext_vector_type(8)));
typedef float f32x4v __attribute__((ext_vector_type(4)));

DEV unsigned short f2h_bits(float f) {
  union { _Float16 h; unsigned short u; } cv;
  cv.h = (_Float16)f;
  return cv.u;
}

// Direct global->LDS 16B async copy. lds base must be WAVE-UNIFORM; lane i
// deposits at lds + i*16. Global source is per-lane (pre-swizzled there).
DEV void gload16(const void* g, void* lds) {
  auto* gp = reinterpret_cast<const __attribute__((address_space(1))) unsigned int*>(
      reinterpret_cast<unsigned long long>(g));
  auto* lp = reinterpret_cast<__attribute__((address_space(3))) unsigned int*>(
      reinterpret_cast<unsigned long long>(lds));
  __builtin_amdgcn_global_load_lds(gp, lp, 16, 0, 0);
}

// ---------------------------------------------------------------------------
// 1. prep: fused independent preprocessing. (R2/R4/R6, passed)
__global__ __launch_bounds__(256) void prep_k(
    const float* __restrict__ W_enc, unsigned short* __restrict__ WencT,
    const float* __restrict__ emb, const float* __restrict__ W_q,
    const float* __restrict__ b_q, float* __restrict__ Qe,
    const float* __restrict__ W_o, const float* __restrict__ W_cls,
    unsigned short* __restrict__ WocT, const float* __restrict__ b_o,
    const float* __restrict__ b_cls, float* __restrict__ boc) {
  __shared__ float plds[2080];              // 8320 B, shared by all phases
  const int blk = blockIdx.x, tid = threadIdx.x;
  if (blk < 96) {
    unsigned short* t = (unsigned short*)plds;    // [64][65]
    const int k0 = (blk % 12) * 64, n0 = (blk / 12) * 64;
    for (int e = tid; e < 4096; e += 256) {
      int kk = e >> 6, nn = e & 63;
      t[kk * 65 + nn] = f2h_bits(W_enc[(size_t)(k0 + kk) * 512 + n0 + nn]);
    }
    __syncthreads();
    for (int e = tid; e < 4096; e += 256) {
      int nn = e >> 6, kk = e & 63;
      WencT[(size_t)(n0 + nn) * 768 + k0 + kk] = t[kk * 65 + nn];
    }
  } else if (blk < 346) {
    float* er = plds;
    const int r0 = (blk - 96) * 4;
    for (int i = tid; i < 2048; i += 256) er[i] = emb[(size_t)r0 * 512 + i];
    __syncthreads();
    const int j0 = tid, j1 = tid + 256;
    float a0[4], a1[4];
#pragma unroll
    for (int r = 0; r < 4; ++r) { a0[r] = 0.f; a1[r] = 0.f; }
    for (int i = 0; i < 512; ++i) {
      float w0 = W_q[i * 512 + j0], w1 = W_q[i * 512 + j1];
#pragma unroll
      for (int r = 0; r < 4; ++r) {
        a0[r] += er[r * 512 + i] * w0;
        a1[r] += er[r * 512 + i] * w1;
      }
    }
    float bq0 = b_q[j0], bq1 = b_q[j1];
#pragma unroll
    for (int r = 0; r < 4; ++r) {
      Qe[(size_t)(r0 + r) * 512 + j0] = a0[r] + bq0;
      Qe[(size_t)(r0 + r) * 512 + j1] = a1[r] + bq1;
    }
  } else if (blk < 474) {
    float* wr = plds;
    const int i0 = (blk - 346) * 4;
    for (int i = tid; i < 2048; i += 256) wr[i] = W_o[(size_t)i0 * 512 + i];
    __syncthreads();
    float a[4][4];
#pragma unroll
    for (int r = 0; r < 4; ++r)
#pragma unroll
      for (int c = 0; c < 4; ++c) a[r][c] = 0.f;
    for (int m = 0; m < 512; ++m) {
      float wc[4];
#pragma unroll
      for (int c = 0; c < 4; ++c) {
        int j = tid + c * 256;
        wc[c] = (j < 1000) ? W_cls[(size_t)m * 1000 + j] : 0.f;
      }
#pragma unroll
      for (int r = 0; r < 4; ++r) {
        float x = wr[r * 512 + m];
#pragma unroll
        for (int c = 0; c < 4; ++c) a[r][c] += x * wc[c];
      }
    }
#pragma unroll
    for (int r = 0; r < 4; ++r)
#pragma unroll
      for (int c = 0; c < 4; ++c) {
        int j = tid + c * 256;
        if (j < 1000) WocT[(size_t)j * 512 + i0 + r] = f2h_bits(a[r][c]);
      }
    if (blk == 346) {  // zero pad rows 1000..1023
      for (int i = tid; i < 24 * 512; i += 256) WocT[512000 + i] = 0;
    }
  } else {
    int j = (blk - 474) * 256 + tid;        // 0..1023
    float s = 0.f;
    if (j < 1000) {
      for (int m = 0; m < 512; ++m) s += b_o[m] * W_cls[(size_t)m * 1000 + j];
      s += b_cls[j];
    }
    boc[j] = s;
  }
}

// ---------------------------------------------------------------------------
// 2. Fused score GEMM (R6 verbatim): 128-row tile, N=512, BK=32, dbuf,
//    16 waves, wave tile 64x64 (acc 4x4).
__global__ __launch_bounds__(1024, 4) void score_gemm(
    const float* __restrict__ vf, const unsigned short* __restrict__ WencT,
    const float* __restrict__ b_enc, const float* __restrict__ W_sel,
    const float* __restrict__ b_sel, float* __restrict__ scores) {
  __shared__ unsigned short As[2][128 * 32];   // 2 x 8 KB, [row][k] swizzled
  __shared__ unsigned short Bs[2][512 * 32];   // 2 x 32 KB, [n][k] swizzled
  __shared__ float red[16 * 64];               // 4 KB

  const int tid = threadIdx.x;
  const int wv = tid >> 6, lane = tid & 63;
  const int quad = lane >> 4, l15 = lane & 15;
  const int wr = wv >> 3, wc = wv & 7;         // wave row-half / col-block
  const int rowBase = blockIdx.x * 128;
  const int rso = ((quad ^ (l15 & 3)) << 4);   // swizzled 16B read slot
  char* const AsB0 = (char*)As[0];
  char* const AsB1 = (char*)As[1];
  char* const BsB0 = (char*)Bs[0];
  char* const BsB1 = (char*)Bs[1];

  f32x4v acc[4][4];
#pragma unroll
  for (int i = 0; i < 4; ++i)
#pragma unroll
    for (int j = 0; j < 4; ++j) acc[i][j] = (f32x4v){0.f, 0.f, 0.f, 0.f};

  // A staging: thread owns row = tid>>3, 4-f32 segment aseg = tid&7.
  const int arow = tid >> 3, aseg = tid & 7;
  const float* aSrc = vf + (size_t)(rowBase + arow) * 768 + aseg * 4;
  const int aslot = aseg >> 1, ahalf = aseg & 1;
  const int adst = arow * 64 + ((aslot ^ (arow & 3)) << 4) + ahalf * 8;

  auto packA = [&](float4 f, char* An) {
    uint2 pk;
    pk.x = (unsigned int)f2h_bits(f.x) | ((unsigned int)f2h_bits(f.y) << 16);
    pk.y = (unsigned int)f2h_bits(f.z) | ((unsigned int)f2h_bits(f.w) << 16);
    *(uint2*)(An + adst) = pk;
  };
  auto stage_b = [&](int kk, char* dstB) {
#pragma unroll
    for (int it = 0; it < 2; ++it) {
      int q = tid + it * 1024;
      int n = q >> 2, seg = q & 3;
      gload16(WencT + (size_t)n * 768 + kk * 32 + ((seg ^ (n & 3)) << 3),
              dstB + (it * 1024 + wv * 64) * 16);
    }
  };
  auto consume = [&](const char* A, const char* B) {
    half8 af[4], bf[4];
#pragma unroll
    for (int i = 0; i < 4; ++i) {
      int row = wr * 64 + 16 * i + l15;
      af[i] = *(const half8*)(A + row * 64 + rso);
    }
#pragma unroll
    for (int j = 0; j < 4; ++j) {
      int n = wc * 64 + 16 * j + l15;
      bf[j] = *(const half8*)(B + n * 64 + rso);
    }
#pragma unroll
    for (int i = 0; i < 4; ++i)
#pragma unroll
      for (int j = 0; j < 4; ++j)
        acc[i][j] = __builtin_amdgcn_mfma_f32_16x16x32_f16(af[i], bf[j], acc[i][j], 0, 0, 0);
  };

  // prologue: stage step 0 into buf0
  stage_b(0, BsB0);
  packA(*(const float4*)(aSrc), AsB0);
  __syncthreads();
  int cur = 0;
  for (int kk = 0; kk < 23; ++kk) {
    float4 fa = *(const float4*)(aSrc + (kk + 1) * 32);   // issue vf load early
    char* An = cur ? AsB0 : AsB1;
    char* Bn = cur ? BsB0 : BsB1;
    stage_b(kk + 1, Bn);                     // async gloads into other buffer
    consume(cur ? AsB1 : AsB0, cur ? BsB1 : BsB0);
    packA(fa, An);                           // pack+write after MFMAs
    __syncthreads();                         // drains vmem+lds for next step
    cur ^= 1;
  }
  consume(cur ? AsB1 : AsB0, cur ? BsB1 : BsB0);

  // epilogue: (x + b_enc) -> relu -> * W_sel -> reduce over cols (== R4 order)
  float be[4], wsv[4];
#pragma unroll
  for (int j = 0; j < 4; ++j) {
    int col = wc * 64 + 16 * j + l15;
    be[j] = b_enc[col];
    wsv[j] = W_sel[col];
  }
  float part[16];
#pragma unroll
  for (int x = 0; x < 16; ++x) part[x] = 0.f;
#pragma unroll
  for (int i = 0; i < 4; ++i)
#pragma unroll
    for (int j = 0; j < 4; ++j)
#pragma unroll
      for (int r = 0; r < 4; ++r) {
        float v = acc[i][j][r] + be[j];   // row=wr*64+16i+quad*4+r, col=wc*64+16j+l15
        v = fmaxf(v, 0.f);
        part[i * 4 + r] += v * wsv[j];
      }
#pragma unroll
  for (int m = 1; m < 16; m <<= 1)
#pragma unroll
    for (int x = 0; x < 16; ++x) part[x] += __shfl_xor(part[x], m);
  if (l15 == 0) {
#pragma unroll
    for (int i = 0; i < 4; ++i)
#pragma unroll
      for (int r = 0; r < 4; ++r)
        red[wv * 64 + 16 * i + quad * 4 + r] = part[i * 4 + r];
  }
  __syncthreads();
  if (tid < 128) {
    const int rh = tid >> 6, rl = tid & 63;
    float s = 0.f;
#pragma unroll
    for (int ww = 0; ww < 8; ++ww) s += red[(rh * 8 + ww) * 64 + rl];
    scores[rowBase + tid] = s + b_sel[0];
  }
}

// ---------------------------------------------------------------------------
// 3. per-batch top-16 candidates (R1 verbatim, passed). 256 threads.
__global__ __launch_bounds__(256) void topk16(const float* __restrict__ scores,
                                              int* __restrict__ cand) {
  __shared__ float swv[4];
  __shared__ int swi[4];
  __shared__ int winner;
  const int b = blockIdx.x, tid = threadIdx.x;
  const int lane = tid & 63, w = tid >> 6;
  float v[16];
#pragma unroll
  for (int p = 0; p < 16; ++p) v[p] = scores[b * 4096 + p * 256 + tid];
  for (int r = 0; r < 16; ++r) {
    float bv = v[0];
    int bp = 0;
#pragma unroll
    for (int p = 1; p < 16; ++p)
      if (v[p] > bv) { bv = v[p]; bp = p; }
    int bi = bp * 256 + tid;
#pragma unroll
    for (int m = 1; m < 64; m <<= 1) {
      float ov = __shfl_xor(bv, m);
      int oi = __shfl_xor(bi, m);
      if (ov > bv || (ov == bv && oi < bi)) { bv = ov; bi = oi; }
    }
    if (lane == 0) { swv[w] = bv; swi[w] = bi; }
    __syncthreads();
    if (tid == 0) {
      float fv = swv[0];
      int fi = swi[0];
#pragma unroll
      for (int x = 1; x < 4; ++x)
        if (swv[x] > fv || (swv[x] == fv && swi[x] < fi)) { fv = swv[x]; fi = swi[x]; }
      cand[b * 16 + r] = fi;
      winner = fi;
    }
    __syncthreads();
    const int wi = winner;
    const int wp = wi >> 8, wt = wi & 255;
#pragma unroll
    for (int p = 0; p < 16; ++p)
      if (p == wp && tid == wt) v[p] = -3.0e38f;
    __syncthreads();
  }
}

// ---------------------------------------------------------------------------
// 4. exact fp32 recompute, one candidate per block. grid (32,16), 256 thr.
//    Derived from R1's proven rescore by removing the c-loop: per-candidate
//    FP chains, reduction pairing, 4-wave partial order all unchanged.
__global__ __launch_bounds__(256) void rescore(
    const float* __restrict__ vf, const int* __restrict__ cand,
    const float* __restrict__ W_enc, const float* __restrict__ b_enc,
    const float* __restrict__ W_sel, const float* __restrict__ b_sel,
    float* __restrict__ veC, float* __restrict__ exsc) {
  __shared__ float vfs[768];                // 3 KB
  __shared__ float redl[4];
  const int b = blockIdx.x, c = blockIdx.y, tid = threadIdx.x;
  const int t = cand[b * 16 + c];
  const float* src = vf + ((size_t)b * 4096 + t) * 768;
  for (int i = tid; i < 768; i += 256) vfs[i] = src[i];
  __syncthreads();
  const int j0 = tid, j1 = tid + 256;
  float a0 = 0.f, a1 = 0.f;
  for (int i = 0; i < 768; ++i) {
    float w0 = W_enc[(size_t)i * 512 + j0], w1 = W_enc[(size_t)i * 512 + j1];
    float x = vfs[i];
    a0 += x * w0;
    a1 += x * w1;
  }
  float ws0 = W_sel[j0], ws1 = W_sel[j1];
  float be0 = b_enc[j0], be1 = b_enc[j1];
  float v0 = fmaxf(a0 + be0, 0.f);
  float v1 = fmaxf(a1 + be1, 0.f);
  veC[((size_t)b * 16 + c) * 512 + j0] = v0;
  veC[((size_t)b * 16 + c) * 512 + j1] = v1;
  float s = v0 * ws0 + v1 * ws1;
#pragma unroll
  for (int m = 1; m < 64; m <<= 1) s += __shfl_xor(s, m);
  int w = tid >> 6;
  if ((tid & 63) == 0) redl[w] = s;
  __syncthreads();
  if (tid == 0)
    exsc[b * 16 + c] = redl[0] + redl[1] + redl[2] + redl[3] + b_sel[0];
}

// ---------------------------------------------------------------------------
// 5. merged select6 + kv_proj (R8, passed): one block per (b, rank).
__global__ __launch_bounds__(256) void selkv_k(
    const float* __restrict__ exsc, const int* __restrict__ cand,
    const float* __restrict__ veC, const float* __restrict__ W_k,
    const float* __restrict__ W_v, const float* __restrict__ b_k,
    const float* __restrict__ b_v, float* __restrict__ repsOut,
    float* __restrict__ Ks, float* __restrict__ Vs) {
  __shared__ float rep[512];
  __shared__ int selc;
  const int br = blockIdx.x;                // b*6 + rk
  const int b = br / 6, rk = br - b * 6;
  const int tid = threadIdx.x;
  if (tid == 0) {
    float v[16]; int idx[16]; bool used[16];
    for (int c = 0; c < 16; ++c) {
      v[c] = exsc[b * 16 + c];
      idx[c] = cand[b * 16 + c];
      used[c] = false;
    }
    int bi = -1;
    for (int r = 0; r <= rk; ++r) {
      bi = -1;
      for (int c = 0; c < 16; ++c) {
        if (used[c]) continue;
        if (bi < 0 || v[c] > v[bi] || (v[c] == v[bi] && idx[c] < idx[bi])) bi = c;
      }
      used[bi] = true;
    }
    selc = bi;
  }
  __syncthreads();
  const int c = selc;
  for (int i = tid; i < 512; i += 256) {
    float x = veC[((size_t)b * 16 + c) * 512 + i];
    repsOut[((size_t)b * 6 + rk) * 512 + i] = x;
    rep[i] = x;
  }
  __syncthreads();
  const int j0 = tid, j1 = tid + 256;
  float k0 = 0.f, k1 = 0.f, v0 = 0.f, v1 = 0.f;
  for (int m = 0; m < 512; ++m) {
    float x = rep[m];
    k0 += x * W_k[m * 512 + j0];
    k1 += x * W_k[m * 512 + j1];
    v0 += x * W_v[m * 512 + j0];
    v1 += x * W_v[m * 512 + j1];
  }
  Ks[(size_t)br * 512 + j0] = (k0 + b_k[j0]) * 0.125f;
  Ks[(size_t)br * 512 + j1] = (k1 + b_k[j1]) * 0.125f;
  Vs[(size_t)br * 512 + j0] = v0 + b_v[j0];
  Vs[(size_t)br * 512 + j1] = v1 + b_v[j1];
}

// ---------------------------------------------------------------------------
// 6. per-token attention over K=6 keys; one wave per token.
__global__ __launch_bounds__(256) void ctx_kernel(
    const int* __restrict__ ids, const float* __restrict__ Qe,
    const float* __restrict__ Ks, const float* __restrict__ Vs,
    unsigned short* __restrict__ CTX) {
  const int token = blockIdx.x * 4 + (threadIdx.x >> 6);
  const int lane = threadIdx.x & 63;
  const int b = token >> 9;                 // L = 512
  const int id = ids[token];
  float q[8];
#pragma unroll
  for (int h = 0; h < 8; ++h) q[h] = Qe[(size_t)id * 512 + h * 64 + lane];
  float s[8][6];
#pragma unroll
  for (int kk = 0; kk < 6; ++kk) {
    const float* kp = Ks + ((size_t)b * 6 + kk) * 512 + lane;
    float p[8];
#pragma unroll
    for (int h = 0; h < 8; ++h) p[h] = q[h] * kp[h * 64];
#pragma unroll
    for (int m = 1; m < 64; m <<= 1)
#pragma unroll
      for (int h = 0; h < 8; ++h) p[h] += __shfl_xor(p[h], m);
#pragma unroll
    for (int h = 0; h < 8; ++h) s[h][kk] = p[h];
  }
  const float* vbase = Vs + (size_t)b * 6 * 512 + lane;
#pragma unroll
  for (int h = 0; h < 8; ++h) {
    float mx = s[h][0];
#pragma unroll
    for (int kk = 1; kk < 6; ++kk) mx = fmaxf(mx, s[h][kk]);
    float e[6], sum = 0.f;
#pragma unroll
    for (int kk = 0; kk < 6; ++kk) { e[kk] = __expf(s[h][kk] - mx); sum += e[kk]; }
    float c = 0.f;
#pragma unroll
    for (int kk = 0; kk < 6; ++kk) c += e[kk] * vbase[(size_t)kk * 512 + h * 64];
    c *= (1.f / sum);
    CTX[(size_t)token * 512 + h * 64 + lane] = f2h_bits(c);
  }
}

// ---------------------------------------------------------------------------
// 7. logits = CTX @ W_oc + b_oc (R6 verbatim): BK=32 dbuf, 16 waves,
//    wave tile 64x64 (acc 4x4).
__global__ __launch_bounds__(1024, 4) void logits_gemm(
    const unsigned short* __restrict__ CTX, const unsigned short* __restrict__ WocT,
    const float* __restrict__ boc, float* __restrict__ out) {
  __shared__ unsigned short As[2][128 * 32];   // 2 x 8 KB
  __shared__ unsigned short Bs[2][512 * 32];   // 2 x 32 KB
  const int tid = threadIdx.x;
  const int wv = tid >> 6, lane = tid & 63;
  const int quad = lane >> 4, l15 = lane & 15;
  const int wr = wv >> 3, wc = wv & 7;
  const int rowBase = blockIdx.x * 128;
  const int n0 = blockIdx.y * 512;
  const int rso = ((quad ^ (l15 & 3)) << 4);
  char* const AsB0 = (char*)As[0];
  char* const AsB1 = (char*)As[1];
  char* const BsB0 = (char*)Bs[0];
  char* const BsB1 = (char*)Bs[1];

  f32x4v acc[4][4];
#pragma unroll
  for (int i = 0; i < 4; ++i)
#pragma unroll
    for (int j = 0; j < 4; ++j) acc[i][j] = (f32x4v){0.f, 0.f, 0.f, 0.f};

  const int arow = tid >> 2, aseg = tid & 3;   // valid for tid<512

  auto stage = [&](int kk, char* An, char* Bn) {
    const int k0 = kk * 32;
    if (wv < 8) {                              // A: 128x32 f16 = 512 chunks
      gload16(CTX + (size_t)(rowBase + arow) * 512 + k0 + ((aseg ^ (arow & 3)) << 3),
              An + wv * 1024);
    }
#pragma unroll
    for (int it = 0; it < 2; ++it) {           // B: 512x32 f16 = 2048 chunks
      int q = tid + it * 1024;
      int n = q >> 2, seg = q & 3;
      gload16(WocT + (size_t)(n0 + n) * 512 + k0 + ((seg ^ (n & 3)) << 3),
              Bn + (it * 1024 + wv * 64) * 16);
    }
  };
  auto consume = [&](const char* A, const char* B) {
    half8 af[4], bf[4];
#pragma unroll
    for (int i = 0; i < 4; ++i) {
      int row = wr * 64 + 16 * i + l15;
      af[i] = *(const half8*)(A + row * 64 + rso);
    }
#pragma unroll
    for (int j = 0; j < 4; ++j) {
      int n = wc * 64 + 16 * j + l15;
      bf[j] = *(const half8*)(B + n * 64 + rso);
    }
#pragma unroll
    for (int i = 0; i < 4; ++i)
#pragma unroll
      for (int j = 0; j < 4; ++j)
        acc[i][j] = __builtin_amdgcn_mfma_f32_16x16x32_f16(af[i], bf[j], acc[i][j], 0, 0, 0);
  };

  stage(0, AsB0, BsB0);
  __syncthreads();
  int cur = 0;
  for (int kk = 0; kk < 15; ++kk) {
    stage(kk + 1, cur ? AsB0 : AsB1, cur ? BsB0 : BsB1);
    consume(cur ? AsB1 : AsB0, cur ? BsB1 : BsB0);
    __syncthreads();
    cur ^= 1;
  }
  consume(cur ? AsB1 : AsB0, cur ? BsB1 : BsB0);

  float bo[4];
#pragma unroll
  for (int j = 0; j < 4; ++j) bo[j] = boc[n0 + wc * 64 + 16 * j + l15];
#pragma unroll
  for (int i = 0; i < 4; ++i)
#pragma unroll
    for (int j = 0; j < 4; ++j)
#pragma unroll
      for (int r = 0; r < 4; ++r) {
        int token = rowBase + wr * 64 + 16 * i + quad * 4 + r;
        int col = n0 + wc * 64 + 16 * j + l15;
        if (col < 1000) out[(size_t)token * 1000 + col] = acc[i][j][r] + bo[j];
      }
}

// ===========================================================================
extern "C" void kernel_launch(void* const* d_in, const int* in_sizes, int n_in,
                              void* d_out, int out_size, void* d_ws, size_t ws_size,
                              hipStream_t stream) {
  (void)in_sizes; (void)n_in; (void)out_size; (void)ws_size;
  const float* vf    = (const float*)d_in[0];
  const int*   ids   = (const int*)d_in[1];
  // d_in[2] attention_mask: unused by reference
  const float* W_enc = (const float*)d_in[3];
  const float* b_enc = (const float*)d_in[4];
  const float* W_sel = (const float*)d_in[5];
  const float* b_sel = (const float*)d_in[6];
  const float* emb   = (const float*)d_in[7];
  const float* W_q   = (const float*)d_in[8];
  const float* W_k   = (const float*)d_in[9];
  const float* W_v   = (const float*)d_in[10];
  const float* b_q   = (const float*)d_in[11];
  const float* b_k   = (const float*)d_in[12];
  const float* b_v   = (const float*)d_in[13];
  const float* W_o   = (const float*)d_in[14];
  const float* b_o   = (const float*)d_in[15];
  const float* W_cls = (const float*)d_in[16];
  const float* b_cls = (const float*)d_in[17];

  float* out = (float*)d_out;                  // logits [32*512*1000]
  float* reps_out = out + (size_t)16384000;    // reps   [32*6*512]

  // workspace carve-up (~24 MB)
  char* p = (char*)d_ws;
  auto nxt = [&](size_t bytes) -> char* {
    char* q = p;
    p += (bytes + 255) & ~(size_t)255;
    return q;
  };
  unsigned short* WencT = (unsigned short*)nxt((size_t)512 * 768 * 2);
  unsigned short* WocT  = (unsigned short*)nxt((size_t)1024 * 512 * 2);
  unsigned short* CTX   = (unsigned short*)nxt((size_t)16384 * 512 * 2);
  float* scores = (float*)nxt((size_t)131072 * 4);
  int*   cand   = (int*)nxt((size_t)512 * 4);
  float* exsc   = (float*)nxt((size_t)512 * 4);
  float* veC    = (float*)nxt((size_t)32 * 16 * 512 * 4);
  float* Ks     = (float*)nxt((size_t)98304 * 4);
  float* Vs     = (float*)nxt((size_t)98304 * 4);
  float* Qe     = (float*)nxt((size_t)512000 * 4);
  float* boc    = (float*)nxt((size_t)1024 * 4);

  hipLaunchKernelGGL(prep_k,      dim3(478),    dim3(256), 0, stream,
                     W_enc, WencT, emb, W_q, b_q, Qe, W_o, W_cls, WocT, b_o, b_cls, boc);
  hipLaunchKernelGGL(score_gemm,  dim3(1024),   dim3(1024), 0, stream,
                     vf, WencT, b_enc, W_sel, b_sel, scores);
  hipLaunchKernelGGL(topk16,      dim3(32),     dim3(256), 0, stream, scores, cand);
  hipLaunchKernelGGL(rescore,     dim3(32, 16), dim3(256), 0, stream,
                     vf, cand, W_enc, b_enc, W_sel, b_sel, veC, exsc);
  hipLaunchKernelGGL(selkv_k,     dim3(192),    dim3(256), 0, stream,
                     exsc, cand, veC, W_k, W_v, b_k, b_v, reps_out, Ks, Vs);
  hipLaunchKernelGGL(ctx_kernel,  dim3(4096),   dim3(256), 0, stream, ids, Qe, Ks, Vs, CTX);
  hipLaunchKernelGGL(logits_gemm, dim3(128, 2), dim3(1024), 0, stream, CTX, WocT, boc, out);
}